// Round 1
// baseline (1171.919 us; speedup 1.0000x reference)
//
#include <hip/hip_runtime.h>
#include <math.h>

#define L 1632
#define NUP 8
#define NB 32
#define NA 64
#define KK 12
#define NW 21          // 2*SEARCH+1
#define RED 408        // L/LOCC
#define NCHUNK 4       // antenna chunks per (u,b) in kernel 1 (16 antennas each)

// ---------------------------------------------------------------------------
// Kernel 1: per (u,b) compute the 21-point power window (sum over antennas of
// |DFT at ideal_peak-10 .. ideal_peak+10|^2) and the noise-diff power sum.
// Grid: 256 ub * 4 antenna-chunks = 1024 blocks, 256 threads.
// Thread (tid): a_local = tid>>4 (16 antennas), s = tid&15 (16 ranges of 102).
// ---------------------------------------------------------------------------
__global__ __launch_bounds__(256) void k1_window(
    const float* __restrict__ lsr, const float* __restrict__ lsi,
    const int* __restrict__ cshift,
    float* __restrict__ winp, float* __restrict__ noisep)
{
    const int blk   = blockIdx.x;
    const int ub    = blk >> 2;          // u*32 + b
    const int chunk = blk & 3;
    const int u     = ub >> 5;
    const int tid   = threadIdx.x;
    const int a     = chunk * 16 + (tid >> 4);
    const int s     = tid & 15;
    const int row   = (ub * NA + a) * L;
    const int n0    = s * 102;           // 1632/16

    __shared__ float lds_win[NW];
    __shared__ float lds_noise;
    if (tid < NW) lds_win[tid] = 0.0f;
    if (tid == NW) lds_noise = 0.0f;
    __syncthreads();

    const int shift = cshift[u];
    const int ip    = ((KK - shift) % KK) * (L / KK);
    int t0 = ip - 10;
    t0 = ((t0 % L) + L) % L;             // first window index (mod L)

    const float cph = (float)(2.0 * M_PI / (double)L);

    float accr[NW], acci[NW];
#pragma unroll
    for (int o = 0; o < NW; o++) { accr[o] = 0.0f; acci[o] = 0.0f; }
    float na  = 0.0f;
    float pxr = 0.0f, pxi = 0.0f;

    for (int n = n0; n < n0 + 102; n++) {
        const float xr = lsr[row + n];
        const float xi = lsi[row + n];
        if (n > n0) { const float dr = xr - pxr, di = xi - pxi; na += dr * dr + di * di; }
        pxr = xr; pxi = xi;
        // w0 = e^{2*pi*i*(n*t0 mod L)/L}, step = e^{2*pi*i*n/L}
        const int idx0 = (n * t0) % L;   // n*t0 <= 1631*1631 < 2^31
        float w0s, w0c, ss, sc;
        __sincosf(cph * (float)idx0, &w0s, &w0c);
        __sincosf(cph * (float)n,    &ss,  &sc);
        float yr = xr * w0c - xi * w0s;
        float yi = xr * w0s + xi * w0c;
#pragma unroll
        for (int o = 0; o < NW; o++) {
            accr[o] += yr; acci[o] += yi;
            const float t = yr * sc - yi * ss;
            yi = yr * ss + yi * sc;
            yr = t;
        }
    }
    if (s < 15) {   // boundary noise pair (n0+101, n0+102)
        const float xr = lsr[row + n0 + 102];
        const float xi = lsi[row + n0 + 102];
        const float dr = xr - pxr, di = xi - pxi;
        na += dr * dr + di * di;
    }

    // reduce over the 16 sub-ranges (lanes with same antenna are consecutive)
#pragma unroll
    for (int m = 1; m < 16; m <<= 1) {
#pragma unroll
        for (int o = 0; o < NW; o++) {
            accr[o] += __shfl_xor(accr[o], m);
            acci[o] += __shfl_xor(acci[o], m);
        }
        na += __shfl_xor(na, m);
    }
    if (s == 0) {
#pragma unroll
        for (int o = 0; o < NW; o++)
            atomicAdd(&lds_win[o], accr[o] * accr[o] + acci[o] * acci[o]);
        atomicAdd(&lds_noise, na);
    }
    __syncthreads();
    if (tid < NW)  winp[blk * NW + tid] = lds_win[tid];
    if (tid == 0)  noisep[blk] = lds_noise;
}

// ---------------------------------------------------------------------------
// Kernel 2: per (u,b): argmax of window -> m -> mm = ((m mod L)+L) mod L;
// noise_pw; Gauss-Jordan inverse of (C + s*I) (SPD, no pivoting) in LDS;
// W = C @ inv. Grid: 256 blocks, 192 threads.
// ---------------------------------------------------------------------------
__global__ __launch_bounds__(192) void k2_wmat(
    const float* __restrict__ winp, const float* __restrict__ noisep,
    const int* __restrict__ cshift,
    float* __restrict__ Wout, int* __restrict__ mmOut)
{
    const int ub  = blockIdx.x;
    const int u   = ub >> 5;
    const int tid = threadIdx.x;
    __shared__ float win[NW];
    __shared__ float Cs[12][12];
    __shared__ float aug[12][25];
    __shared__ float snoise;

    if (tid < NW) {
        float v = 0.0f;
#pragma unroll
        for (int c = 0; c < NCHUNK; c++) v += winp[(ub * NCHUNK + c) * NW + tid];
        win[tid] = v;
    }
    if (tid == NW) {
        float ns = 0.0f;
#pragma unroll
        for (int c = 0; c < NCHUNK; c++) ns += noisep[ub * NCHUNK + c];
        snoise = ns / (float)NA / (float)(L - 1) / 2.0f;
    }
    if (tid >= 32 && tid < 32 + 144) {
        const int t = tid - 32;
        const int i = t / 12, j = t % 12;
        const int d = (i > j) ? (i - j) : (j - i);
        double v = 1.0;
        for (int k = 0; k < d; k++) v *= 0.9;   // RHO^|i-j| in double, cast f32
        Cs[i][j] = (float)v;
    }
    __syncthreads();

    if (tid < 144) {
        const int i = tid / 12, j = tid % 12;
        aug[i][j]      = Cs[i][j] + ((i == j) ? snoise : 0.0f);
        aug[i][12 + j] = (i == j) ? 1.0f : 0.0f;
    }
    __syncthreads();

    // Gauss-Jordan, threads 0..23 own augmented columns
    for (int k = 0; k < 12; k++) {
        float pv = 1.0f, rowkj = 0.0f;
        float fcol[12];
        if (tid < 24) {
            pv    = aug[k][k];
            rowkj = aug[k][tid];
#pragma unroll
            for (int i = 0; i < 12; i++) fcol[i] = aug[i][k];
        }
        __syncthreads();
        if (tid < 24) {
            const float nrm = rowkj / pv;
            aug[k][tid] = nrm;
#pragma unroll
            for (int i = 0; i < 12; i++)
                if (i != k) aug[i][tid] -= fcol[i] * nrm;
        }
        __syncthreads();
    }

    if (tid == 0) {   // argmax (first occurrence) -> mm
        float best = win[0];
        int bo = 0;
        for (int o = 1; o < NW; o++)
            if (win[o] > best) { best = win[o]; bo = o; }
        const int shift = cshift[u];
        const int ip = ((KK - shift) % KK) * (L / KK);
        const int m = ip + (bo - 10);
        mmOut[ub] = ((m % L) + L) % L;
    }

    if (tid < 144) {   // W = C @ inv
        const int i = tid / 12, j = tid % 12;
        float w = 0.0f;
#pragma unroll
        for (int k = 0; k < 12; k++) w += Cs[i][k] * aug[k][12 + j];
        Wout[ub * 144 + tid] = w;
    }
}

// ---------------------------------------------------------------------------
// Kernel 3: per (u,b,a) row: phase-rotate, 4-average, linear interp, 12x12
// Wiener smoothing, write interleaved re/im. Grid: 16384 blocks, 256 threads.
// ---------------------------------------------------------------------------
__global__ __launch_bounds__(256) void k3_main(
    const float* __restrict__ lsr, const float* __restrict__ lsi,
    const float* __restrict__ Wall, const int* __restrict__ mmArr,
    float* __restrict__ out)
{
    const int bid = blockIdx.x;     // (u*32+b)*64 + a
    const int ub  = bid >> 6;
    const int row = bid * L;
    const int tid = threadIdx.x;
    __shared__ float2 havg[RED];
    __shared__ float2 hint[L];
    __shared__ float  Wl[144];
    if (tid < 144) Wl[tid] = Wall[ub * 144 + tid];
    const int mm = mmArr[ub];
    const float cph = (float)(2.0 * M_PI / (double)L);

    // h_avg[r] = mean over 4 of ls[n] * e^{2*pi*i*(mm*n mod L)/L}
    for (int r = tid; r < RED; r += 256) {
        const int base = 4 * r;
        const float4 xr = *reinterpret_cast<const float4*>(lsr + row + base);
        const float4 xi = *reinterpret_cast<const float4*>(lsi + row + base);
        int idx = (mm * base) % L;      // mm*base < 2^31
        float ar = 0.0f, ai = 0.0f, sn, cs;
        __sincosf(cph * (float)idx, &sn, &cs);
        ar += xr.x * cs - xi.x * sn; ai += xr.x * sn + xi.x * cs;
        idx += mm; if (idx >= L) idx -= L;
        __sincosf(cph * (float)idx, &sn, &cs);
        ar += xr.y * cs - xi.y * sn; ai += xr.y * sn + xi.y * cs;
        idx += mm; if (idx >= L) idx -= L;
        __sincosf(cph * (float)idx, &sn, &cs);
        ar += xr.z * cs - xi.z * sn; ai += xr.z * sn + xi.z * cs;
        idx += mm; if (idx >= L) idx -= L;
        __sincosf(cph * (float)idx, &sn, &cs);
        ar += xr.w * cs - xi.w * sn; ai += xr.w * sn + xi.w * cs;
        havg[r] = make_float2(ar * 0.25f, ai * 0.25f);
    }
    __syncthreads();

    // linear interpolation back to L samples (weights bit-exact vs reference)
    for (int t = tid; t < L; t += 256) {
        float p = ((float)t - 1.5f) * 0.25f;
        p = fminf(fmaxf(p, 0.0f), 407.0f);
        int i0 = (int)p;
        if (i0 > 406) i0 = 406;
        const float fr = p - (float)i0;
        const float2 h0 = havg[i0], h1 = havg[i0 + 1];
        hint[t] = make_float2(h0.x * (1.0f - fr) + h1.x * fr,
                              h0.y * (1.0f - fr) + h1.y * fr);
    }
    __syncthreads();

    // Wiener: out[j*12+i] = sum_k W[i][k] * hint[j*12+k]
    float2* o2 = reinterpret_cast<float2*>(out);
    for (int e = tid; e < L; e += 256) {
        const int j = e / 12;
        const int i = e - j * 12;
        const float* wr = &Wl[i * 12];
        float ax = 0.0f, ay = 0.0f;
#pragma unroll
        for (int k = 0; k < 12; k++) {
            const float  w = wr[k];
            const float2 h = hint[j * 12 + k];
            ax += w * h.x; ay += w * h.y;
        }
        o2[row + e] = make_float2(ax, ay);
    }
}

// ---------------------------------------------------------------------------
extern "C" void kernel_launch(void* const* d_in, const int* in_sizes, int n_in,
                              void* d_out, int out_size, void* d_ws, size_t ws_size,
                              hipStream_t stream) {
    const float* lsr    = (const float*)d_in[0];
    const float* lsi    = (const float*)d_in[1];
    const int*   cshift = (const int*)d_in[2];
    float* out = (float*)d_out;

    char* ws = (char*)d_ws;
    float* Wout   = (float*)(ws);                              // 256*144*4 = 147456 B
    float* winp   = (float*)(ws + 147456);                     // 1024*21*4 =  86016 B
    float* noisep = (float*)(ws + 147456 + 86016);             // 1024*4    =   4096 B
    int*   mmArr  = (int*)  (ws + 147456 + 86016 + 4096);      // 256*4     =   1024 B

    hipLaunchKernelGGL(k1_window, dim3(NUP * NB * NCHUNK), dim3(256), 0, stream,
                       lsr, lsi, cshift, winp, noisep);
    hipLaunchKernelGGL(k2_wmat, dim3(NUP * NB), dim3(192), 0, stream,
                       winp, noisep, cshift, Wout, mmArr);
    hipLaunchKernelGGL(k3_main, dim3(NUP * NB * NA), dim3(256), 0, stream,
                       lsr, lsi, Wout, mmArr, out);
}

// Round 2
// 504.844 us; speedup vs baseline: 2.3213x; 2.3213x over previous
//
#include <hip/hip_runtime.h>
#include <math.h>

#define L 1632
#define NUP 8
#define NB 32
#define NA 64
#define KK 12
#define NW 21          // 2*SEARCH+1
#define RED 408        // L/LOCC

// ---------------------------------------------------------------------------
// Kernel 1: one wave per (ub, antenna) row. Lane l handles n = 4l + 256k,
// k = 0..6 (fully coalesced float4 loads). Computes the 21-point DFT window
// (|sum_n x_n e^{2pi i n (t0+o)/L}|^2 summed over antennas via atomics) and
// the noise first-difference power.
// Grid: 256 ub * 16 chunks of 4 antennas = 4096 blocks, 256 threads (4 waves).
// ---------------------------------------------------------------------------
__global__ __launch_bounds__(256) void k1_window(
    const float* __restrict__ lsr, const float* __restrict__ lsi,
    const int* __restrict__ cshift,
    float* __restrict__ winp, float* __restrict__ noisep)
{
    const int bid   = blockIdx.x;
    const int ub    = bid >> 4;          // u*32 + b
    const int chunk = bid & 15;
    const int u     = ub >> 5;
    const int tid   = threadIdx.x;
    const int wave  = tid >> 6;
    const int lane  = tid & 63;
    const int a     = chunk * 4 + wave;
    const int row   = (ub * NA + a) * L;

    const int shift = cshift[u];
    const int ip    = ((KK - shift) % KK) * (L / KK);
    int t0 = ip - 10;
    t0 = ((t0 % L) + L) % L;

    const float cph = (float)(2.0 * M_PI / (double)L);

    float accr[NW], acci[NW];
#pragma unroll
    for (int o = 0; o < NW; o++) { accr[o] = 0.0f; acci[o] = 0.0f; }
    float na = 0.0f;
    float carry_r = 0.0f, carry_i = 0.0f;

#define ELEM(XR, XI, N) { \
    const int idx0 = ((N) * t0) % L; \
    float s0, c0, s1, c1; \
    __sincosf(cph * (float)idx0, &s0, &c0); \
    __sincosf(cph * (float)(N),  &s1, &c1); \
    float yr = (XR) * c0 - (XI) * s0; \
    float yi = (XR) * s0 + (XI) * c0; \
    _Pragma("unroll") \
    for (int o = 0; o < NW; o++) { \
        accr[o] += yr; acci[o] += yi; \
        const float t_ = yr * c1 - yi * s1; \
        yi = yr * s1 + yi * c1; yr = t_; } }

    for (int k = 0; k < 7; k++) {
        const int nb  = 256 * k + 4 * lane;
        const bool act = (nb < L);
        float4 xr = make_float4(0.f, 0.f, 0.f, 0.f);
        float4 xi = make_float4(0.f, 0.f, 0.f, 0.f);
        if (act) {
            xr = *reinterpret_cast<const float4*>(lsr + row + nb);
            xi = *reinterpret_cast<const float4*>(lsi + row + nb);
        }
        // neighbor (n-1) values: lane l-1's .w, or lane 63's .w of prev iter
        const float c63r = __shfl(carry_r, 63);
        const float c63i = __shfl(carry_i, 63);
        const float upr  = __shfl_up(xr.w, 1);
        const float upi  = __shfl_up(xi.w, 1);
        const float pr   = (lane == 0) ? c63r : upr;
        const float pi   = (lane == 0) ? c63i : upi;
        if (act) {
            if (!(k == 0 && lane == 0)) {
                const float dr = xr.x - pr, di = xi.x - pi; na += dr * dr + di * di;
            }
            { const float dr = xr.y - xr.x, di = xi.y - xi.x; na += dr * dr + di * di; }
            { const float dr = xr.z - xr.y, di = xi.z - xi.y; na += dr * dr + di * di; }
            { const float dr = xr.w - xr.z, di = xi.w - xi.z; na += dr * dr + di * di; }
        }
        carry_r = xr.w; carry_i = xi.w;
        // DFT contributions (inactive lanes carry x=0 -> contribute 0)
        ELEM(xr.x, xi.x, nb + 0)
        ELEM(xr.y, xi.y, nb + 1)
        ELEM(xr.z, xi.z, nb + 2)
        ELEM(xr.w, xi.w, nb + 3)
    }
#undef ELEM

    // full-wave butterfly reduction (row == wave, so this completes the row sum)
#pragma unroll
    for (int m = 1; m < 64; m <<= 1) {
#pragma unroll
        for (int o = 0; o < NW; o++) {
            accr[o] += __shfl_xor(accr[o], m);
            acci[o] += __shfl_xor(acci[o], m);
        }
        na += __shfl_xor(na, m);
    }

    if (lane == 0) {
#pragma unroll
        for (int o = 0; o < NW; o++)
            atomicAdd(&winp[ub * NW + o], accr[o] * accr[o] + acci[o] * acci[o]);
        atomicAdd(&noisep[ub], na);
    }
}

// ---------------------------------------------------------------------------
// Kernel 2: per (u,b): argmax of window -> mm; noise_pw; Gauss-Jordan inverse
// of (C + s*I) in LDS; W = C @ inv. Grid: 256 blocks, 192 threads.
// ---------------------------------------------------------------------------
__global__ __launch_bounds__(192) void k2_wmat(
    const float* __restrict__ winp, const float* __restrict__ noisep,
    const int* __restrict__ cshift,
    float* __restrict__ Wout, int* __restrict__ mmOut)
{
    const int ub  = blockIdx.x;
    const int u   = ub >> 5;
    const int tid = threadIdx.x;
    __shared__ float win[NW];
    __shared__ float Cs[12][12];
    __shared__ float aug[12][25];
    __shared__ float snoise;

    if (tid < NW) win[tid] = winp[ub * NW + tid];
    if (tid == NW) snoise = noisep[ub] / (float)NA / (float)(L - 1) / 2.0f;
    if (tid >= 32 && tid < 32 + 144) {
        const int t = tid - 32;
        const int i = t / 12, j = t % 12;
        const int d = (i > j) ? (i - j) : (j - i);
        double v = 1.0;
        for (int k = 0; k < d; k++) v *= 0.9;   // RHO^|i-j|
        Cs[i][j] = (float)v;
    }
    __syncthreads();

    if (tid < 144) {
        const int i = tid / 12, j = tid % 12;
        aug[i][j]      = Cs[i][j] + ((i == j) ? snoise : 0.0f);
        aug[i][12 + j] = (i == j) ? 1.0f : 0.0f;
    }
    __syncthreads();

    for (int k = 0; k < 12; k++) {
        float pv = 1.0f, rowkj = 0.0f;
        float fcol[12];
        if (tid < 24) {
            pv    = aug[k][k];
            rowkj = aug[k][tid];
#pragma unroll
            for (int i = 0; i < 12; i++) fcol[i] = aug[i][k];
        }
        __syncthreads();
        if (tid < 24) {
            const float nrm = rowkj / pv;
            aug[k][tid] = nrm;
#pragma unroll
            for (int i = 0; i < 12; i++)
                if (i != k) aug[i][tid] -= fcol[i] * nrm;
        }
        __syncthreads();
    }

    if (tid == 0) {
        float best = win[0];
        int bo = 0;
        for (int o = 1; o < NW; o++)
            if (win[o] > best) { best = win[o]; bo = o; }
        const int shift = cshift[u];
        const int ip = ((KK - shift) % KK) * (L / KK);
        const int m = ip + (bo - 10);
        mmOut[ub] = ((m % L) + L) % L;
    }

    if (tid < 144) {
        const int i = tid / 12, j = tid % 12;
        float w = 0.0f;
#pragma unroll
        for (int k = 0; k < 12; k++) w += Cs[i][k] * aug[k][12 + j];
        Wout[ub * 144 + tid] = w;
    }
}

// ---------------------------------------------------------------------------
// Kernel 3: per (u,b,a) row: phase-rotate, 4-average, linear interp, 12x12
// Wiener smoothing, write interleaved re/im. Grid: 16384 blocks, 256 threads.
// ---------------------------------------------------------------------------
__global__ __launch_bounds__(256) void k3_main(
    const float* __restrict__ lsr, const float* __restrict__ lsi,
    const float* __restrict__ Wall, const int* __restrict__ mmArr,
    float* __restrict__ out)
{
    const int bid = blockIdx.x;     // (u*32+b)*64 + a
    const int ub  = bid >> 6;
    const int row = bid * L;
    const int tid = threadIdx.x;
    __shared__ float2 havg[RED];
    __shared__ float2 hint[L];
    __shared__ float  Wl[144];
    if (tid < 144) Wl[tid] = Wall[ub * 144 + tid];
    const int mm = mmArr[ub];
    const float cph = (float)(2.0 * M_PI / (double)L);

    for (int r = tid; r < RED; r += 256) {
        const int base = 4 * r;
        const float4 xr = *reinterpret_cast<const float4*>(lsr + row + base);
        const float4 xi = *reinterpret_cast<const float4*>(lsi + row + base);
        int idx = (mm * base) % L;
        float ar = 0.0f, ai = 0.0f, sn, cs;
        __sincosf(cph * (float)idx, &sn, &cs);
        ar += xr.x * cs - xi.x * sn; ai += xr.x * sn + xi.x * cs;
        idx += mm; if (idx >= L) idx -= L;
        __sincosf(cph * (float)idx, &sn, &cs);
        ar += xr.y * cs - xi.y * sn; ai += xr.y * sn + xi.y * cs;
        idx += mm; if (idx >= L) idx -= L;
        __sincosf(cph * (float)idx, &sn, &cs);
        ar += xr.z * cs - xi.z * sn; ai += xr.z * sn + xi.z * cs;
        idx += mm; if (idx >= L) idx -= L;
        __sincosf(cph * (float)idx, &sn, &cs);
        ar += xr.w * cs - xi.w * sn; ai += xr.w * sn + xi.w * cs;
        havg[r] = make_float2(ar * 0.25f, ai * 0.25f);
    }
    __syncthreads();

    for (int t = tid; t < L; t += 256) {
        float p = ((float)t - 1.5f) * 0.25f;
        p = fminf(fmaxf(p, 0.0f), 407.0f);
        int i0 = (int)p;
        if (i0 > 406) i0 = 406;
        const float fr = p - (float)i0;
        const float2 h0 = havg[i0], h1 = havg[i0 + 1];
        hint[t] = make_float2(h0.x * (1.0f - fr) + h1.x * fr,
                              h0.y * (1.0f - fr) + h1.y * fr);
    }
    __syncthreads();

    float2* o2 = reinterpret_cast<float2*>(out);
    for (int e = tid; e < L; e += 256) {
        const int j = e / 12;
        const int i = e - j * 12;
        const float* wr = &Wl[i * 12];
        float ax = 0.0f, ay = 0.0f;
#pragma unroll
        for (int k = 0; k < 12; k++) {
            const float  w = wr[k];
            const float2 h = hint[j * 12 + k];
            ax += w * h.x; ay += w * h.y;
        }
        o2[row + e] = make_float2(ax, ay);
    }
}

// ---------------------------------------------------------------------------
extern "C" void kernel_launch(void* const* d_in, const int* in_sizes, int n_in,
                              void* d_out, int out_size, void* d_ws, size_t ws_size,
                              hipStream_t stream) {
    const float* lsr    = (const float*)d_in[0];
    const float* lsi    = (const float*)d_in[1];
    const int*   cshift = (const int*)d_in[2];
    float* out = (float*)d_out;

    char* ws = (char*)d_ws;
    float* Wout   = (float*)(ws);                          // 256*144*4 = 147456 B
    float* winp   = (float*)(ws + 147456);                 // 256*21*4  =  21504 B
    float* noisep = (float*)(ws + 147456 + 21504);         // 256*4     =   1024 B
    int*   mmArr  = (int*)  (ws + 147456 + 21504 + 1024);  // 256*4     =   1024 B

    // zero the atomic accumulators (memset node is graph-capturable)
    hipMemsetAsync(winp, 0, 21504 + 1024, stream);

    hipLaunchKernelGGL(k1_window, dim3(NUP * NB * 16), dim3(256), 0, stream,
                       lsr, lsi, cshift, winp, noisep);
    hipLaunchKernelGGL(k2_wmat, dim3(NUP * NB), dim3(192), 0, stream,
                       winp, noisep, cshift, Wout, mmArr);
    hipLaunchKernelGGL(k3_main, dim3(NUP * NB * NA), dim3(256), 0, stream,
                       lsr, lsi, Wout, mmArr, out);
}